// Round 13
// baseline (92.686 us; speedup 1.0000x reference)
//
#include <hip/hip_runtime.h>
#include <cfloat>
#include <cmath>

// Problem constants (match reference)
#define IC 480        // IN_CHANNELS
#define OC 18         // OUT_CHANNELS
#define HH 256
#define WW 256
#define HW_ 65536     // H*W
#define NPROP 30      // MAX_PROPOSALS
#define NCG 8         // channel groups for the dot kernel (round-6 proven)
#define CPG 60        // channels per group (480/8)
#define CAP 6144      // candidate capacity (expected survivors ~2600)

// MEASUREMENT ROUND: k_dot is launched 3x (idempotent, deterministic).
// (T_total - 53.5) / 2 = k_dot duration + node gap. This resolves whether
// k_dot is at its HBM floor (~20us) or has ~10us of BW headroom — the one
// unknown that decides between further k_dot work and declaring roofline.

// ---------------------------------------------------------------------------
// K1: partial dot products  partial[cg][p] = sum_{c in group} f[c,p]*w17[c]
// float4 loads; grid (64, 8) x 256 = 512 blocks; unroll 15.
// Block (0,0) zeroes the candidate counter.
// ---------------------------------------------------------------------------
__global__ __launch_bounds__(256) void k_dot(const float* __restrict__ f,
                                             const float* __restrict__ w,
                                             float* __restrict__ partial,
                                             int* __restrict__ counter) {
    __shared__ float sw[CPG];
    const int tid = threadIdx.x;
    const int cg = blockIdx.y;
    const int c0 = cg * CPG;
    if (tid < CPG) sw[tid] = w[17 * IC + c0 + tid];
    if (blockIdx.x == 0 && cg == 0 && tid == 0) *counter = 0;
    __syncthreads();
    const int p4 = blockIdx.x * 256 + tid;            // float4 index [0,16384)
    const float4* __restrict__ f4 = (const float4*)f;
    float ax = 0.f, ay = 0.f, az = 0.f, aw = 0.f;
    #pragma unroll 15
    for (int c = 0; c < CPG; ++c) {
        float4 v = f4[(size_t)(c0 + c) * (HW_ / 4) + p4];
        float wc = sw[c];
        ax = fmaf(v.x, wc, ax);
        ay = fmaf(v.y, wc, ay);
        az = fmaf(v.z, wc, az);
        aw = fmaf(v.w, wc, aw);
    }
    float4 r; r.x = ax; r.y = ay; r.z = az; r.w = aw;
    ((float4*)partial)[(size_t)cg * (HW_ / 4) + p4] = r;
}

// ---------------------------------------------------------------------------
// K2: fused  center = clip(sigmoid(sum+b));  c2 = (center + avg3(center))/2;
//     NMS: survivor iff c2 == max5(c2) -> atomic append of PACKED u64 key.
// ---------------------------------------------------------------------------
__global__ __launch_bounds__(256) void k_pool(const float* __restrict__ partial,
                                              const float* __restrict__ conv_b,
                                              unsigned long long* __restrict__ cand,
                                              int* __restrict__ counter) {
    __shared__ float sc[14][38];            // center tile, halo 3
    __shared__ float s2[12][36];            // c2 tile, halo 2
    const int tid = threadIdx.x;
    const int ox = (blockIdx.x & 7) * 32, oy = (blockIdx.x >> 3) * 8;
    const float b = conv_b[OC - 1];

    for (int i = tid; i < 14 * 38; i += 256) {
        int ly = i / 38, lx = i % 38;
        int gy = oy - 3 + ly, gx = ox - 3 + lx;
        float v = 0.f;                                   // zero pad (avg-sum)
        if (gy >= 0 && gy < HH && gx >= 0 && gx < WW) {
            int p = gy * WW + gx;
            float raw = b;
            #pragma unroll
            for (int g = 0; g < NCG; ++g) raw += partial[g * HW_ + p];
            float s = 1.f / (1.f + expf(-raw));
            v = fminf(fmaxf(s, 1e-4f), 1.f - 1e-4f);
        }
        sc[ly][lx] = v;
    }
    __syncthreads();

    for (int i = tid; i < 12 * 36; i += 256) {
        int ly = i / 36, lx = i % 36;
        int gy = oy - 2 + ly, gx = ox - 2 + lx;
        float v = -FLT_MAX;                              // -inf pad (max)
        if (gy >= 0 && gy < HH && gx >= 0 && gx < WW) {
            float sum = 0.f;
            #pragma unroll
            for (int dy = 0; dy < 3; ++dy)
                #pragma unroll
                for (int dx = 0; dx < 3; ++dx)
                    sum += sc[ly + dy][lx + dx];
            v = (sc[ly + 1][lx + 1] + sum / 9.0f) * 0.5f;
        }
        s2[ly][lx] = v;
    }
    __syncthreads();

    const int tx = tid & 31, ty = tid >> 5;
    float c = s2[ty + 2][tx + 2];
    float m = -FLT_MAX;
    #pragma unroll
    for (int dy = 0; dy < 5; ++dy)
        #pragma unroll
        for (int dx = 0; dx < 5; ++dx)
            m = fmaxf(m, s2[ty + dy][tx + dx]);
    if (m == c) {                                        // survivor (c > 0)
        int slot = atomicAdd(counter, 1);
        if (slot < CAP) {
            unsigned pix = (unsigned)((oy + ty) * WW + (ox + tx));
            cand[slot] = ((unsigned long long)__float_as_uint(c) << 32)
                       | (unsigned long long)(0xFFFFFFFFu - pix);
        }
    }
}

// ---------------------------------------------------------------------------
// Bitonic helpers (ascending u64 order == value asc + index desc -> top of
// list = value desc, lower-index ties — exact lax.top_k semantics).
// ---------------------------------------------------------------------------
__device__ __forceinline__ unsigned long long bsort64(unsigned long long key,
                                                      int lane) {
    #pragma unroll
    for (int k = 2; k <= 64; k <<= 1) {
        #pragma unroll
        for (int j = k >> 1; j > 0; j >>= 1) {
            unsigned long long o = __shfl_xor(key, j);
            bool lower = (lane & j) == 0;
            bool asc   = (lane & k) == 0;
            unsigned long long mn = key < o ? key : o;
            unsigned long long mx = key < o ? o : key;
            key = (lower == asc) ? mn : mx;
        }
    }
    return key;   // ascending across lanes
}

__device__ __forceinline__ unsigned long long bmerge64(unsigned long long key,
                                                       int lane) {
    #pragma unroll
    for (int j = 32; j > 0; j >>= 1) {
        unsigned long long o = __shfl_xor(key, j);
        bool lower = (lane & j) == 0;
        unsigned long long mn = key < o ? key : o;
        unsigned long long mx = key < o ? o : key;
        key = lower ? mn : mx;
    }
    return key;   // sorts a bitonic sequence ascending
}

// ---------------------------------------------------------------------------
// K3: single-block top-30 (512 threads, 8 waves; candidates pre-packed).
// ---------------------------------------------------------------------------
__global__ __launch_bounds__(512) void k_select(
        const unsigned long long* __restrict__ cand,
        const int* __restrict__ counter,
        float* __restrict__ out, int* __restrict__ selpix) {
    __shared__ unsigned long long lk[512];
    const int tid = threadIdx.x;
    const int lane = tid & 63, wv = tid >> 6;
    int n = *counter; if (n > CAP) n = CAP;

    unsigned long long R = 0;   // all-zero list is sorted ascending
    for (int base = wv * 64; base < n; base += 512) {
        int j = base + lane;
        unsigned long long key = (j < n) ? cand[j] : 0;
        key = bsort64(key, lane);                 // chunk ascending
        unsigned long long crev = __shfl_xor(key, 63);
        R = R > crev ? R : crev;                  // top-64 of union (bitonic)
        R = bmerge64(R, lane);                    // re-sort ascending
    }
    lk[tid] = R;
    __syncthreads();

    if (wv == 0) {
        R = lk[lane];
        #pragma unroll
        for (int w = 1; w < 8; ++w) {
            unsigned long long c = lk[w * 64 + lane];
            unsigned long long crev = __shfl_xor(c, 63);
            R = R > crev ? R : crev;
            R = bmerge64(R, lane);
        }
        int r = 63 - lane;                        // rank r lives at lane 63-r
        if (r < NPROP) {
            float s = 0.f; int p = 0;
            if (R != 0) {
                s = __uint_as_float((unsigned)(R >> 32));
                p = (int)(0xFFFFFFFFu - (unsigned)(R & 0xFFFFFFFFu));
            }
            out[2 * r]     = (float)(p >> 8);     // y
            out[2 * r + 1] = (float)(p & 255);    // x
            out[60 + r] = s;                      // score
            out[60 + NPROP + NPROP * IC + r] = (s > 0.01f) ? 1.f : 0.f;
            selpix[r] = p;
        }
    }
}

// ---------------------------------------------------------------------------
// K4: gather instance_param in (480, 30) layout: out[90 + c*30 + i] = f[c, p_i]
// ---------------------------------------------------------------------------
__global__ __launch_bounds__(256) void k_gather(const float* __restrict__ f,
                                                const int* __restrict__ selpix,
                                                float* __restrict__ out) {
    __shared__ int sp[NPROP];
    const int tid = threadIdx.x;
    if (tid < NPROP) sp[tid] = selpix[tid];
    __syncthreads();
    int idx = blockIdx.x * 256 + tid;                 // 0 .. 14399
    if (idx < IC * NPROP) {
        int c = idx / NPROP, i = idx % NPROP;
        out[60 + NPROP + idx] = f[(size_t)c * HW_ + sp[i]];
    }
}

extern "C" void kernel_launch(void* const* d_in, const int* in_sizes, int n_in,
                              void* d_out, int out_size, void* d_ws, size_t ws_size,
                              hipStream_t stream) {
    const float* features = (const float*)d_in[0];
    const float* conv_w   = (const float*)d_in[1];
    const float* conv_b   = (const float*)d_in[2];
    float* out = (float*)d_out;
    char* ws = (char*)d_ws;

    // ws layout (~2.05 MB total)
    float*              partial = (float*)ws;                        // 2 MB
    unsigned long long* cand    = (unsigned long long*)(ws + (2 << 20)); // 48 KB
    int*                counter = (int*)(ws + (2 << 20) + CAP * 8);  // 4 B
    int*                selpix  = (int*)(ws + (2 << 20) + CAP * 8 + 16); // 120 B

    // --- k_dot x3: measurement (idempotent; Δ/2 = k_dot + gap) ---
    k_dot   <<<dim3(HW_ / 1024, NCG), 256, 0, stream>>>(features, conv_w,
                                                        partial, counter);
    k_dot   <<<dim3(HW_ / 1024, NCG), 256, 0, stream>>>(features, conv_w,
                                                        partial, counter);
    k_dot   <<<dim3(HW_ / 1024, NCG), 256, 0, stream>>>(features, conv_w,
                                                        partial, counter);
    k_pool  <<<256, 256, 0, stream>>>(partial, conv_b, cand, counter);
    k_select<<<1, 512, 0, stream>>>(cand, counter, out, selpix);
    k_gather<<<(IC * NPROP + 255) / 256, 256, 0, stream>>>(features, selpix, out);
}

// Round 14
// 52.894 us; speedup vs baseline: 1.7523x; 1.7523x over previous
//
#include <hip/hip_runtime.h>
#include <cfloat>
#include <cmath>

// Problem constants (match reference)
#define IC 480        // IN_CHANNELS
#define OC 18         // OUT_CHANNELS
#define HH 256
#define WW 256
#define HW_ 65536     // H*W
#define NPROP 30      // MAX_PROPOSALS
#define NCG 8         // channel groups for the dot kernel (round-6 proven)
#define CPG 60        // channels per group (480/8)
#define CAP 6144      // candidate capacity (expected survivors ~2600)

// Output layout (14520 floats):
//   [0,60)        instance_coord (30,2) (y,x)
//   [60,90)       scores (30,)
//   [90,14490)    instance_param (480,30)  channels-major (features[0,:,y,x].T)
//   [14490,14520) valid (30,)

// Round-13 measurement: k_dot (kernel+gap) = 19.6us = 126MB at >=6.4TB/s ->
// AT the HBM/L3 roofline. Remaining target is the tail: select's 27-stage
// dependent-shuffle cost (~5us) is paid once either way; replicating it into
// the gather blocks at 512 threads (5 chunks/wave, NOT round-11's 256-thread
// 10-chunk mistake) removes one node boundary + the gather node.

// ---------------------------------------------------------------------------
// K1: partial dot products  partial[cg][p] = sum_{c in group} f[c,p]*w17[c]
// float4 loads; grid (64, 8) x 256 = 512 blocks; unroll 15.
// Block (0,0) zeroes the candidate counter.
// ---------------------------------------------------------------------------
__global__ __launch_bounds__(256) void k_dot(const float* __restrict__ f,
                                             const float* __restrict__ w,
                                             float* __restrict__ partial,
                                             int* __restrict__ counter) {
    __shared__ float sw[CPG];
    const int tid = threadIdx.x;
    const int cg = blockIdx.y;
    const int c0 = cg * CPG;
    if (tid < CPG) sw[tid] = w[17 * IC + c0 + tid];
    if (blockIdx.x == 0 && cg == 0 && tid == 0) *counter = 0;
    __syncthreads();
    const int p4 = blockIdx.x * 256 + tid;            // float4 index [0,16384)
    const float4* __restrict__ f4 = (const float4*)f;
    float ax = 0.f, ay = 0.f, az = 0.f, aw = 0.f;
    #pragma unroll 15
    for (int c = 0; c < CPG; ++c) {
        float4 v = f4[(size_t)(c0 + c) * (HW_ / 4) + p4];
        float wc = sw[c];
        ax = fmaf(v.x, wc, ax);
        ay = fmaf(v.y, wc, ay);
        az = fmaf(v.z, wc, az);
        aw = fmaf(v.w, wc, aw);
    }
    float4 r; r.x = ax; r.y = ay; r.z = az; r.w = aw;
    ((float4*)partial)[(size_t)cg * (HW_ / 4) + p4] = r;
}

// ---------------------------------------------------------------------------
// K2: fused  center = clip(sigmoid(sum+b));  c2 = (center + avg3(center))/2;
//     NMS: survivor iff c2 == max5(c2) -> atomic append of PACKED u64 key
//     (val_bits<<32 | ~pixel).
// ---------------------------------------------------------------------------
__global__ __launch_bounds__(256) void k_pool(const float* __restrict__ partial,
                                              const float* __restrict__ conv_b,
                                              unsigned long long* __restrict__ cand,
                                              int* __restrict__ counter) {
    __shared__ float sc[14][38];            // center tile, halo 3
    __shared__ float s2[12][36];            // c2 tile, halo 2
    const int tid = threadIdx.x;
    const int ox = (blockIdx.x & 7) * 32, oy = (blockIdx.x >> 3) * 8;
    const float b = conv_b[OC - 1];

    for (int i = tid; i < 14 * 38; i += 256) {
        int ly = i / 38, lx = i % 38;
        int gy = oy - 3 + ly, gx = ox - 3 + lx;
        float v = 0.f;                                   // zero pad (avg-sum)
        if (gy >= 0 && gy < HH && gx >= 0 && gx < WW) {
            int p = gy * WW + gx;
            float raw = b;
            #pragma unroll
            for (int g = 0; g < NCG; ++g) raw += partial[g * HW_ + p];
            float s = 1.f / (1.f + expf(-raw));
            v = fminf(fmaxf(s, 1e-4f), 1.f - 1e-4f);
        }
        sc[ly][lx] = v;
    }
    __syncthreads();

    for (int i = tid; i < 12 * 36; i += 256) {
        int ly = i / 36, lx = i % 36;
        int gy = oy - 2 + ly, gx = ox - 2 + lx;
        float v = -FLT_MAX;                              // -inf pad (max)
        if (gy >= 0 && gy < HH && gx >= 0 && gx < WW) {
            float sum = 0.f;
            #pragma unroll
            for (int dy = 0; dy < 3; ++dy)
                #pragma unroll
                for (int dx = 0; dx < 3; ++dx)
                    sum += sc[ly + dy][lx + dx];
            v = (sc[ly + 1][lx + 1] + sum / 9.0f) * 0.5f;
        }
        s2[ly][lx] = v;
    }
    __syncthreads();

    const int tx = tid & 31, ty = tid >> 5;
    float c = s2[ty + 2][tx + 2];
    float m = -FLT_MAX;
    #pragma unroll
    for (int dy = 0; dy < 5; ++dy)
        #pragma unroll
        for (int dx = 0; dx < 5; ++dx)
            m = fmaxf(m, s2[ty + dy][tx + dx]);
    if (m == c) {                                        // survivor (c > 0)
        int slot = atomicAdd(counter, 1);
        if (slot < CAP) {
            unsigned pix = (unsigned)((oy + ty) * WW + (ox + tx));
            cand[slot] = ((unsigned long long)__float_as_uint(c) << 32)
                       | (unsigned long long)(0xFFFFFFFFu - pix);
        }
    }
}

// ---------------------------------------------------------------------------
// Bitonic helpers (ascending u64 order == value asc + index desc -> top of
// list = value desc, lower-index ties — exact lax.top_k semantics,
// invariant to atomic append order).
// ---------------------------------------------------------------------------
__device__ __forceinline__ unsigned long long bsort64(unsigned long long key,
                                                      int lane) {
    #pragma unroll
    for (int k = 2; k <= 64; k <<= 1) {
        #pragma unroll
        for (int j = k >> 1; j > 0; j >>= 1) {
            unsigned long long o = __shfl_xor(key, j);
            bool lower = (lane & j) == 0;
            bool asc   = (lane & k) == 0;
            unsigned long long mn = key < o ? key : o;
            unsigned long long mx = key < o ? o : key;
            key = (lower == asc) ? mn : mx;
        }
    }
    return key;   // ascending across lanes
}

__device__ __forceinline__ unsigned long long bmerge64(unsigned long long key,
                                                       int lane) {
    #pragma unroll
    for (int j = 32; j > 0; j >>= 1) {
        unsigned long long o = __shfl_xor(key, j);
        bool lower = (lane & j) == 0;
        unsigned long long mn = key < o ? key : o;
        unsigned long long mx = key < o ? o : key;
        key = lower ? mn : mx;
    }
    return key;   // sorts a bitonic sequence ascending
}

// ---------------------------------------------------------------------------
// K3: replicated select + fused gather. 29 blocks x 512 threads.
// Every block runs the full 8-wave bitonic top-30 on the packed candidate
// list (pure function of the list -> identical result in all blocks; ~5
// chunks/wave, same cost as the old dedicated select node). Block 0 writes
// coords/scores/valid; every block then gathers its 512-element slice of the
// (480,30) channels-major param matrix (~1 scattered load/thread, spread
// across 29 CUs).
// ---------------------------------------------------------------------------
__global__ __launch_bounds__(512) void k_selgather(
        const unsigned long long* __restrict__ cand,
        const int* __restrict__ counter,
        const float* __restrict__ f,
        float* __restrict__ out) {
    __shared__ unsigned long long lk[512];
    __shared__ int spix[NPROP];
    const int tid = threadIdx.x;
    const int lane = tid & 63, wv = tid >> 6;
    int n = *counter; if (n > CAP) n = CAP;

    unsigned long long R = 0;   // all-zero list is sorted ascending
    for (int base = wv * 64; base < n; base += 512) {
        int j = base + lane;
        unsigned long long key = (j < n) ? cand[j] : 0;
        key = bsort64(key, lane);                 // chunk ascending
        unsigned long long crev = __shfl_xor(key, 63);
        R = R > crev ? R : crev;                  // top-64 of union (bitonic)
        R = bmerge64(R, lane);                    // re-sort ascending
    }
    lk[tid] = R;
    __syncthreads();

    if (wv == 0) {
        R = lk[lane];
        #pragma unroll
        for (int w = 1; w < 8; ++w) {
            unsigned long long c = lk[w * 64 + lane];
            unsigned long long crev = __shfl_xor(c, 63);
            R = R > crev ? R : crev;
            R = bmerge64(R, lane);
        }
        int r = 63 - lane;                        // rank r lives at lane 63-r
        if (r < NPROP) {
            float s = 0.f; int p = 0;
            if (R != 0) {
                s = __uint_as_float((unsigned)(R >> 32));
                p = (int)(0xFFFFFFFFu - (unsigned)(R & 0xFFFFFFFFu));
            }
            spix[r] = p;
            if (blockIdx.x == 0) {
                out[2 * r]     = (float)(p >> 8);     // y
                out[2 * r + 1] = (float)(p & 255);    // x
                out[60 + r] = s;                      // score
                out[60 + NPROP + NPROP * IC + r] = (s > 0.01f) ? 1.f : 0.f;
            }
        }
    }
    __syncthreads();

    // ---- gather slice: out[90 + idx] = f[c, spix[i]], idx = c*30 + i ----
    int idx = blockIdx.x * 512 + tid;             // 0 .. 14399
    if (idx < IC * NPROP) {
        int c = idx / NPROP, i = idx % NPROP;
        out[60 + NPROP + idx] = f[(size_t)c * HW_ + spix[i]];
    }
}

extern "C" void kernel_launch(void* const* d_in, const int* in_sizes, int n_in,
                              void* d_out, int out_size, void* d_ws, size_t ws_size,
                              hipStream_t stream) {
    const float* features = (const float*)d_in[0];
    const float* conv_w   = (const float*)d_in[1];
    const float* conv_b   = (const float*)d_in[2];
    float* out = (float*)d_out;
    char* ws = (char*)d_ws;

    // ws layout (~2.05 MB total)
    float*              partial = (float*)ws;                        // 2 MB
    unsigned long long* cand    = (unsigned long long*)(ws + (2 << 20)); // 48 KB
    int*                counter = (int*)(ws + (2 << 20) + CAP * 8);  // 4 B

    k_dot      <<<dim3(HW_ / 1024, NCG), 256, 0, stream>>>(features, conv_w,
                                                           partial, counter);
    k_pool     <<<256, 256, 0, stream>>>(partial, conv_b, cand, counter);
    k_selgather<<<(IC * NPROP + 511) / 512, 512, 0, stream>>>(cand, counter,
                                                              features, out);
}